// Round 7
// baseline (347.408 us; speedup 1.0000x reference)
//
#include <hip/hip_runtime.h>
#include <math.h>

#define B_G   256
#define IN_D  128
#define FD    256
#define HID   256
#define OUT_D 128
#define TXT   512
#define XKS   136   // X/Z LDS k-stride (ushorts): 272 B/row, 16B-aligned

typedef short bf16x8 __attribute__((ext_vector_type(8)));
typedef float f32x4  __attribute__((ext_vector_type(4)));

// ---------------------------------------------------------------------------
// bf16 split helpers (RNE)
// ---------------------------------------------------------------------------
__device__ __forceinline__ unsigned bf_rne(float x) {
    unsigned u = __float_as_uint(x);
    u += 0x7fffu + ((u >> 16) & 1u);
    return u >> 16;
}
__device__ __forceinline__ float bf_to_f(unsigned h) {
    return __uint_as_float(h << 16);
}
__device__ __forceinline__ void split2(float a0, float a1, unsigned& hp, unsigned& lp) {
    unsigned h0 = bf_rne(a0), h1 = bf_rne(a1);
    float r0 = a0 - bf_to_f(h0), r1 = a1 - bf_to_f(h1);
    hp = h0 | (h1 << 16);
    lp = bf_rne(r0) | (bf_rne(r1) << 16);
}

// ---------------------------------------------------------------------------
// Kernel A (grid 265): fused prep.  blocks 0..255 also zero the per-graph
// completion counters used by k_l0's stats tail.
// ---------------------------------------------------------------------------
__global__ __launch_bounds__(256) void k_prepA(
    const float* __restrict__ text_emb, const float* __restrict__ Wq,
    const float* __restrict__ bq, const float* __restrict__ Wk,
    const float* __restrict__ W0, const float* __restrict__ W2,
    const int* __restrict__ lens,
    float* __restrict__ qk, int* __restrict__ offsets, float* __restrict__ hsum,
    int* __restrict__ cntr,
    unsigned short* __restrict__ W0sH, unsigned short* __restrict__ W0sL,
    unsigned short* __restrict__ W2sH, unsigned short* __restrict__ W2sL)
{
    int blk = blockIdx.x, t = threadIdx.x;
    __shared__ float te[TXT];
    __shared__ float q[FD];
    __shared__ int   sc[B_G];

    if (blk < 256) {
        int b = blk;
        hsum[b * FD + t] = 0.f;
        if (t == 0) cntr[b] = 0;
        for (int i = t; i < TXT; i += 256) te[i] = text_emb[(size_t)b * TXT + i];
        __syncthreads();
        float acc = bq[t];
        for (int k = 0; k < TXT; k++) acc = fmaf(te[k], Wq[k * FD + t], acc);
        q[t] = acc;
        __syncthreads();
        float a2 = 0.f;
        for (int f = 0; f < FD; f++) a2 = fmaf(Wk[t * FD + f], q[f], a2);
        qk[b * FD + t] = a2;
    } else if (blk < 264) {
        int e = (blk - 256) * 256 + t;   // 0..2047
        if (e < 1024) {
            int kc = e >> 8, c = e & 255;
            size_t base = (size_t)(kc * 256 + c) * 32;
            for (int kk = 0; kk < 32; kk++) {
                float v = W0[(size_t)(kc * 32 + kk) * FD + c];
                unsigned h = bf_rne(v);
                float r = v - bf_to_f(h);
                W0sH[base + kk] = (unsigned short)h;
                W0sL[base + kk] = (unsigned short)bf_rne(r);
            }
        } else {
            int e2 = e - 1024;
            int kc = e2 >> 7, c = e2 & 127;
            size_t base = (size_t)(kc * 128 + c) * 32;
            for (int kk = 0; kk < 32; kk++) {
                float v = W2[(size_t)(kc * 32 + kk) * OUT_D + c];
                unsigned h = bf_rne(v);
                float r = v - bf_to_f(h);
                W2sH[base + kk] = (unsigned short)h;
                W2sL[base + kk] = (unsigned short)bf_rne(r);
            }
        }
    } else {
        // parallel inclusive scan of lens (256 elements, 8 steps)
        sc[t] = lens[t];
        __syncthreads();
        for (int d = 1; d < 256; d <<= 1) {
            int v = (t >= d) ? sc[t - d] : 0;
            __syncthreads();
            sc[t] += v;
            __syncthreads();
        }
        offsets[t + 1] = sc[t];
        if (t == 0) offsets[0] = 0;
    }
}

// ---------------------------------------------------------------------------
// K1: bf16x3 MFMA + B-register-prefetch + fused per-graph stats tail.
//  The LAST of the 6 x-blocks of graph b (device-scope counter) computes
//  softmax stats + wvec = (hsum@Wv + len*bv)@Wo inline -> k_graph removed.
// ---------------------------------------------------------------------------
__global__ __launch_bounds__(256, 4) void k_l0_mfma(
    const float* __restrict__ X,
    const unsigned short* __restrict__ W0sH, const unsigned short* __restrict__ W0sL,
    const float* __restrict__ b0, const float* __restrict__ qk,
    const int* __restrict__ offsets,
    const float* __restrict__ Wv, const float* __restrict__ bv,
    const float* __restrict__ Wo,
    float* __restrict__ scores, float* __restrict__ hsum,
    int* __restrict__ cntr,
    float* __restrict__ wvec, float* __restrict__ smax, float* __restrict__ dinv)
{
    int b = blockIdx.y;
    int off = offsets[b], len = offsets[b + 1] - off;
    int n0 = blockIdx.x * 64;

    __shared__ __align__(16) unsigned short XsH[64 * XKS], XsL[64 * XKS]; // 2x17408 B
    __shared__ float qks[FD];
    __shared__ float bsh[FD];
    __shared__ float red[4][64];
    __shared__ float hs[FD], vs[FD];
    __shared__ float redm[4], reds[4];
    __shared__ int   isLast;

    int tid = threadIdx.x;
    int lane = tid & 63, w = tid >> 6;
    int ln = lane & 15, quad = lane >> 4;

    if (n0 < len) {
        int nvalid = min(64, len - n0);
        qks[tid] = qk[b * FD + tid];
        bsh[tid] = b0[tid];

        // ---- stage X: thread -> node tid>>2, k-range (tid&3)*32..+32 ----
        {
            int node_s = tid >> 2, ks = (tid & 3) * 32;
            const float4* Xr4 = (const float4*)(X + (size_t)(off + n0 + node_s) * IN_D + ks);
            bool v = (node_s < nvalid);
#pragma unroll
            for (int g = 0; g < 4; g++) {
                float4 a, c4;
                if (v) { a = Xr4[2 * g]; c4 = Xr4[2 * g + 1]; }
                else   { a = make_float4(0.f, 0.f, 0.f, 0.f); c4 = a; }
                uint4 hq, lq;
                split2(a.x,  a.y,  hq.x, lq.x);
                split2(a.z,  a.w,  hq.y, lq.y);
                split2(c4.x, c4.y, hq.z, lq.z);
                split2(c4.z, c4.w, hq.w, lq.w);
                *(uint4*)&XsH[node_s * XKS + ks + g * 8] = hq;
                *(uint4*)&XsL[node_s * XKS + ks + g * 8] = lq;
            }
        }
        __syncthreads();

        f32x4 acc[4][4] = {};
#pragma unroll
        for (int kc = 0; kc < 4; kc++) {
            bf16x8 AH[4], AL[4];
#pragma unroll
            for (int i = 0; i < 4; i++) {
                AH[i] = *(const bf16x8*)&XsH[(16 * i + ln) * XKS + kc * 32 + quad * 8];
                AL[i] = *(const bf16x8*)&XsL[(16 * i + ln) * XKS + kc * 32 + quad * 8];
            }
            // prefetch B(j=0)
            bf16x8 BH, BL;
            {
                int c = 64 * w + ln;
                size_t base = (size_t)(kc * 256 + c) * 32 + quad * 8;
                BH = *(const bf16x8*)&W0sH[base];
                BL = *(const bf16x8*)&W0sL[base];
            }
#pragma unroll
            for (int j = 0; j < 4; j++) {
                bf16x8 BHn, BLn;
                if (j < 3) {   // prefetch B(j+1) before this j's MFMAs
                    int c = 64 * w + 16 * (j + 1) + ln;
                    size_t base = (size_t)(kc * 256 + c) * 32 + quad * 8;
                    BHn = *(const bf16x8*)&W0sH[base];
                    BLn = *(const bf16x8*)&W0sL[base];
                }
#pragma unroll
                for (int i = 0; i < 4; i++) {
                    acc[i][j] = __builtin_amdgcn_mfma_f32_16x16x32_bf16(AH[i], BH, acc[i][j], 0, 0, 0);
                    acc[i][j] = __builtin_amdgcn_mfma_f32_16x16x32_bf16(AH[i], BL, acc[i][j], 0, 0, 0);
                    acc[i][j] = __builtin_amdgcn_mfma_f32_16x16x32_bf16(AL[i], BH, acc[i][j], 0, 0, 0);
                }
                BH = BHn; BL = BLn;
            }
        }

        // ---- epilogue: bias+relu+mask -> score partials & column sums ----
        float sp[4][4];
        float cs[4] = {0.f, 0.f, 0.f, 0.f};
#pragma unroll
        for (int i = 0; i < 4; i++)
#pragma unroll
            for (int r = 0; r < 4; r++) sp[i][r] = 0.f;

#pragma unroll
        for (int i = 0; i < 4; i++)
#pragma unroll
            for (int j = 0; j < 4; j++) {
                int c = 64 * w + 16 * j + ln;
                float bb = bsh[c], qv = qks[c];
#pragma unroll
                for (int r = 0; r < 4; r++) {
                    int node = 16 * i + 4 * quad + r;
                    float h = acc[i][j][r] + bb;
                    h = (h > 0.f && node < nvalid) ? h : 0.f;
                    sp[i][r] = fmaf(h, qv, sp[i][r]);
                    cs[j] += h;
                }
            }
#pragma unroll
        for (int i = 0; i < 4; i++)
#pragma unroll
            for (int r = 0; r < 4; r++) {
                float s = sp[i][r];
                s += __shfl_xor(s, 1); s += __shfl_xor(s, 2);
                s += __shfl_xor(s, 4); s += __shfl_xor(s, 8);
                sp[i][r] = s;
            }
        if (ln == 0) {
#pragma unroll
            for (int i = 0; i < 4; i++)
#pragma unroll
                for (int r = 0; r < 4; r++)
                    red[w][16 * i + 4 * quad + r] = sp[i][r];
        }
#pragma unroll
        for (int j = 0; j < 4; j++) {
            float s = cs[j];
            s += __shfl_xor(s, 16); s += __shfl_xor(s, 32);
            if (quad == 0) atomicAdd(&hsum[b * FD + 64 * w + 16 * j + ln], s);
        }
        __syncthreads();
        if (tid < 64 && tid < nvalid)
            scores[off + n0 + tid] = red[0][tid] + red[1][tid] + red[2][tid] + red[3][tid];
    }

    // ---- tail election: last of the 6 x-blocks of graph b does the stats ----
    __threadfence();                 // release this block's scores/hsum
    __syncthreads();
    if (tid == 0) {
        int prev = atomicAdd(&cntr[b], 1);
        isLast = (prev == 5);
    }
    __syncthreads();
    if (!isLast) return;
    __threadfence();                 // acquire other blocks' scores/hsum

    // ---- stats tail (256 threads): softmax max/sum + wvec GEMV ----
    {
        float m = -INFINITY;
        for (int i = tid; i < len; i += 256) m = fmaxf(m, scores[off + i]);
#pragma unroll
        for (int d = 1; d < 64; d <<= 1) m = fmaxf(m, __shfl_xor(m, d));
        if (lane == 0) redm[w] = m;
        hs[tid] = hsum[b * FD + tid];
        __syncthreads();
        m = fmaxf(fmaxf(redm[0], redm[1]), fmaxf(redm[2], redm[3]));

        float s = 0.f;
        for (int i = tid; i < len; i += 256) s += expf(scores[off + i] - m);
#pragma unroll
        for (int d = 1; d < 64; d <<= 1) s += __shfl_xor(s, d);
        if (lane == 0) reds[w] = s;
        __syncthreads();
        s = reds[0] + reds[1] + reds[2] + reds[3];

        float acc = (float)len * bv[tid];
        for (int f = 0; f < FD; f++) acc = fmaf(hs[f], Wv[f * FD + tid], acc);
        vs[tid] = acc;
        __syncthreads();
        float a2 = 0.f;
        for (int f = 0; f < HID; f++) a2 = fmaf(vs[f], Wo[f * HID + tid], a2);
        wvec[b * HID + tid] = a2;
        if (tid == 0) { smax[b] = m; dinv[b] = 1.0f / s; }
    }
}

// ---------------------------------------------------------------------------
// K3: bf16x3 MFMA fin, K-tiled Z (37.6 KB LDS, 4 blocks/CU) + B-prefetch.
// ---------------------------------------------------------------------------
__global__ __launch_bounds__(256, 4) void k_fin_mfma(
    const float* __restrict__ scores, const float* __restrict__ wvec,
    const float* __restrict__ bo,
    const unsigned short* __restrict__ W2sH, const unsigned short* __restrict__ W2sL,
    const float* __restrict__ b2, const float* __restrict__ smax,
    const float* __restrict__ dinv, const int* __restrict__ offsets,
    float* __restrict__ Y)
{
    int b = blockIdx.y;
    int off = offsets[b], len = offsets[b + 1] - off;
    int n0 = blockIdx.x * 64;
    if (n0 >= len) return;
    int nvalid = min(64, len - n0);

    int tid = threadIdx.x;
    int lane = tid & 63, w = tid >> 6;
    int ln = lane & 15, quad = lane >> 4;

    __shared__ __align__(16) unsigned short ZsH[64 * XKS], ZsL[64 * XKS]; // 2x17408 B
    __shared__ float ps[64];
    __shared__ float wsh[HID];
    __shared__ float bosh[HID];
    __shared__ float b2sh[OUT_D];

    wsh[tid] = wvec[b * HID + tid];
    bosh[tid] = bo[tid];
    if (tid < OUT_D) b2sh[tid] = b2[tid];
    if (tid < 64) {
        float p = 0.f;
        if (tid < nvalid) p = expf(scores[off + n0 + tid] - smax[b]) * dinv[b];
        ps[tid] = p;
    }
    __syncthreads();

    f32x4 acc[4][2] = {};
    int node_s = tid >> 2, ks = (tid & 3) * 32;

#pragma unroll
    for (int h = 0; h < 2; h++) {
        if (h) __syncthreads();
        // ---- generate Z half [64 nodes][128 k] ----
        {
            float pn = ps[node_s];
            int kg0 = h * 128 + ks;
#pragma unroll
            for (int g = 0; g < 4; g++) {
                uint4 hq, lq;
                int kb = kg0 + g * 8;
                float z0, z1;
                z0 = fmaxf(fmaf(pn, wsh[kb + 0], bosh[kb + 0]), 0.f);
                z1 = fmaxf(fmaf(pn, wsh[kb + 1], bosh[kb + 1]), 0.f);
                split2(z0, z1, hq.x, lq.x);
                z0 = fmaxf(fmaf(pn, wsh[kb + 2], bosh[kb + 2]), 0.f);
                z1 = fmaxf(fmaf(pn, wsh[kb + 3], bosh[kb + 3]), 0.f);
                split2(z0, z1, hq.y, lq.y);
                z0 = fmaxf(fmaf(pn, wsh[kb + 4], bosh[kb + 4]), 0.f);
                z1 = fmaxf(fmaf(pn, wsh[kb + 5], bosh[kb + 5]), 0.f);
                split2(z0, z1, hq.z, lq.z);
                z0 = fmaxf(fmaf(pn, wsh[kb + 6], bosh[kb + 6]), 0.f);
                z1 = fmaxf(fmaf(pn, wsh[kb + 7], bosh[kb + 7]), 0.f);
                split2(z0, z1, hq.w, lq.w);
                *(uint4*)&ZsH[node_s * XKS + ks + g * 8] = hq;
                *(uint4*)&ZsL[node_s * XKS + ks + g * 8] = lq;
            }
        }
        __syncthreads();

        // preload B(kc=0, both j)
        bf16x8 BH[2], BL[2];
#pragma unroll
        for (int j = 0; j < 2; j++) {
            int c = 32 * w + 16 * j + ln;
            size_t base = (size_t)((h * 4) * 128 + c) * 32 + quad * 8;
            BH[j] = *(const bf16x8*)&W2sH[base];
            BL[j] = *(const bf16x8*)&W2sL[base];
        }
#pragma unroll
        for (int kc = 0; kc < 4; kc++) {
            bf16x8 AH[4], AL[4];
#pragma unroll
            for (int i = 0; i < 4; i++) {
                AH[i] = *(const bf16x8*)&ZsH[(16 * i + ln) * XKS + kc * 32 + quad * 8];
                AL[i] = *(const bf16x8*)&ZsL[(16 * i + ln) * XKS + kc * 32 + quad * 8];
            }
            bf16x8 BHn[2], BLn[2];
            if (kc < 3) {   // prefetch B(kc+1) before this kc's MFMAs
#pragma unroll
                for (int j = 0; j < 2; j++) {
                    int c = 32 * w + 16 * j + ln;
                    size_t base = (size_t)((h * 4 + kc + 1) * 128 + c) * 32 + quad * 8;
                    BHn[j] = *(const bf16x8*)&W2sH[base];
                    BLn[j] = *(const bf16x8*)&W2sL[base];
                }
            }
#pragma unroll
            for (int j = 0; j < 2; j++) {
#pragma unroll
                for (int i = 0; i < 4; i++) {
                    acc[i][j] = __builtin_amdgcn_mfma_f32_16x16x32_bf16(AH[i], BH[j], acc[i][j], 0, 0, 0);
                    acc[i][j] = __builtin_amdgcn_mfma_f32_16x16x32_bf16(AH[i], BL[j], acc[i][j], 0, 0, 0);
                    acc[i][j] = __builtin_amdgcn_mfma_f32_16x16x32_bf16(AL[i], BH[j], acc[i][j], 0, 0, 0);
                }
            }
#pragma unroll
            for (int j = 0; j < 2; j++) { BH[j] = BHn[j]; BL[j] = BLn[j]; }
        }
    }

    // ---- epilogue: + b2, masked store ----
#pragma unroll
    for (int i = 0; i < 4; i++)
#pragma unroll
        for (int j = 0; j < 2; j++) {
            int c = 32 * w + 16 * j + ln;
            float bb = b2sh[c];
#pragma unroll
            for (int r = 0; r < 4; r++) {
                int node = 16 * i + 4 * quad + r;
                if (node < nvalid)
                    Y[(size_t)(off + n0 + node) * OUT_D + c] = acc[i][j][r] + bb;
            }
        }
}

// ---------------------------------------------------------------------------
extern "C" void kernel_launch(void* const* d_in, const int* in_sizes, int n_in,
                              void* d_out, int out_size, void* d_ws, size_t ws_size,
                              hipStream_t stream)
{
    const float* X        = (const float*)d_in[0];
    const float* text_emb = (const float*)d_in[1];
    const int*   lens     = (const int*)d_in[2];
    const float* W0       = (const float*)d_in[3];
    const float* b0       = (const float*)d_in[4];
    const float* Wq       = (const float*)d_in[5];
    const float* bq       = (const float*)d_in[6];
    const float* Wk       = (const float*)d_in[7];
    // d_in[8] = bk : softmax-invariant, unused
    const float* Wv       = (const float*)d_in[9];
    const float* bv       = (const float*)d_in[10];
    const float* Wo       = (const float*)d_in[11];
    const float* bo       = (const float*)d_in[12];
    const float* W2       = (const float*)d_in[13];
    const float* b2       = (const float*)d_in[14];
    float* Y = (float*)d_out;

    char* base = (char*)d_ws;
    size_t o = 0;
    int*   offsets = (int*)(base + o);            o += 1088;
    float* qkbuf   = (float*)(base + o);          o += 262144;
    float* wvecb   = (float*)(base + o);          o += 262144;
    float* smaxb   = (float*)(base + o);          o += 1024;
    float* dinvb   = (float*)(base + o);          o += 1024;
    float* hsum    = (float*)(base + o);          o += 262144;
    float* scores  = (float*)(base + o);          o += 262144;
    int*   cntr    = (int*)(base + o);            o += 1024;
    unsigned short* W0sH = (unsigned short*)(base + o); o += 65536;
    unsigned short* W0sL = (unsigned short*)(base + o); o += 65536;
    unsigned short* W2sH = (unsigned short*)(base + o); o += 65536;
    unsigned short* W2sL = (unsigned short*)(base + o); o += 65536;

    k_prepA<<<265, 256, 0, stream>>>(text_emb, Wq, bq, Wk, W0, W2, lens,
                                     qkbuf, offsets, hsum, cntr, W0sH, W0sL, W2sH, W2sL);
    k_l0_mfma<<<dim3(6, B_G), 256, 0, stream>>>(X, W0sH, W0sL, b0, qkbuf, offsets,
                                                Wv, bv, Wo, scores, hsum, cntr,
                                                wvecb, smaxb, dinvb);
    k_fin_mfma<<<dim3(6, B_G), 256, 0, stream>>>(scores, wvecb, bo, W2sH, W2sL, b2,
                                                 smaxb, dinvb, offsets, Y);
}

// Round 8
// 189.782 us; speedup vs baseline: 1.8306x; 1.8306x over previous
//
#include <hip/hip_runtime.h>
#include <math.h>

#define B_G   256
#define IN_D  128
#define FD    256
#define HID   256
#define OUT_D 128
#define TXT   512
#define XKS   136   // X/Z LDS k-stride (ushorts): 272 B/row, 16B-aligned, <=2-way bank

typedef short bf16x8 __attribute__((ext_vector_type(8)));
typedef float f32x4  __attribute__((ext_vector_type(4)));

// ---------------------------------------------------------------------------
// bf16 split helpers (RNE)
// ---------------------------------------------------------------------------
__device__ __forceinline__ unsigned bf_rne(float x) {
    unsigned u = __float_as_uint(x);
    u += 0x7fffu + ((u >> 16) & 1u);
    return u >> 16;
}
__device__ __forceinline__ float bf_to_f(unsigned h) {
    return __uint_as_float(h << 16);
}
__device__ __forceinline__ void split2(float a0, float a1, unsigned& hp, unsigned& lp) {
    unsigned h0 = bf_rne(a0), h1 = bf_rne(a1);
    float r0 = a0 - bf_to_f(h0), r1 = a1 - bf_to_f(h1);
    hp = h0 | (h1 << 16);
    lp = bf_rne(r0) | (bf_rne(r1) << 16);
}

// ---------------------------------------------------------------------------
// Kernel A (grid 265): fused prep.  (R0 verbatim)
//  blocks 0..255  : q_b = te@Wq+bq ; qk_b = Wk@q_b ; zero hsum[b]
//  blocks 256..263: split W0/W2 into fragment-layout hi/lo bf16 buffers
//  block  264     : parallel scan of lens -> offsets
// ---------------------------------------------------------------------------
__global__ __launch_bounds__(256) void k_prepA(
    const float* __restrict__ text_emb, const float* __restrict__ Wq,
    const float* __restrict__ bq, const float* __restrict__ Wk,
    const float* __restrict__ W0, const float* __restrict__ W2,
    const int* __restrict__ lens,
    float* __restrict__ qk, int* __restrict__ offsets, float* __restrict__ hsum,
    unsigned short* __restrict__ W0sH, unsigned short* __restrict__ W0sL,
    unsigned short* __restrict__ W2sH, unsigned short* __restrict__ W2sL)
{
    int blk = blockIdx.x, t = threadIdx.x;
    __shared__ float te[TXT];
    __shared__ float q[FD];
    __shared__ int   sc[B_G];

    if (blk < 256) {
        int b = blk;
        hsum[b * FD + t] = 0.f;
        for (int i = t; i < TXT; i += 256) te[i] = text_emb[(size_t)b * TXT + i];
        __syncthreads();
        float acc = bq[t];
        for (int k = 0; k < TXT; k++) acc = fmaf(te[k], Wq[k * FD + t], acc);
        q[t] = acc;
        __syncthreads();
        float a2 = 0.f;
        for (int f = 0; f < FD; f++) a2 = fmaf(Wk[t * FD + f], q[f], a2);
        qk[b * FD + t] = a2;
    } else if (blk < 264) {
        int e = (blk - 256) * 256 + t;   // 0..2047
        if (e < 1024) {
            int kc = e >> 8, c = e & 255;
            size_t base = (size_t)(kc * 256 + c) * 32;
            for (int kk = 0; kk < 32; kk++) {
                float v = W0[(size_t)(kc * 32 + kk) * FD + c];
                unsigned h = bf_rne(v);
                float r = v - bf_to_f(h);
                W0sH[base + kk] = (unsigned short)h;
                W0sL[base + kk] = (unsigned short)bf_rne(r);
            }
        } else {
            int e2 = e - 1024;
            int kc = e2 >> 7, c = e2 & 127;
            size_t base = (size_t)(kc * 128 + c) * 32;
            for (int kk = 0; kk < 32; kk++) {
                float v = W2[(size_t)(kc * 32 + kk) * OUT_D + c];
                unsigned h = bf_rne(v);
                float r = v - bf_to_f(h);
                W2sH[base + kk] = (unsigned short)h;
                W2sL[base + kk] = (unsigned short)bf_rne(r);
            }
        }
    } else {
        // parallel inclusive scan of lens (256 elements, 8 steps)
        sc[t] = lens[t];
        __syncthreads();
        for (int d = 1; d < 256; d <<= 1) {
            int v = (t >= d) ? sc[t - d] : 0;
            __syncthreads();
            sc[t] += v;
            __syncthreads();
        }
        offsets[t + 1] = sc[t];
        if (t == 0) offsets[0] = 0;
    }
}

// ---------------------------------------------------------------------------
// K1: bf16x3 MFMA, barrier-free K-loop.  (R0 v1 verbatim: (256,2), bulk
// B-fragment loads — measured fastest l0 variant; v3's per-j loads regressed)
// ---------------------------------------------------------------------------
__global__ __launch_bounds__(256, 2) void k_l0_mfma(
    const float* __restrict__ X,
    const unsigned short* __restrict__ W0sH, const unsigned short* __restrict__ W0sL,
    const float* __restrict__ b0, const float* __restrict__ qk,
    const int* __restrict__ offsets,
    float* __restrict__ scores, float* __restrict__ hsum)
{
    int b = blockIdx.y;
    int off = offsets[b], len = offsets[b + 1] - off;
    int n0 = blockIdx.x * 64;
    if (n0 >= len) return;
    int nvalid = min(64, len - n0);

    __shared__ __align__(16) unsigned short XsH[64 * XKS], XsL[64 * XKS]; // 2x17408 B
    __shared__ float qks[FD];
    __shared__ float bsh[FD];
    __shared__ float red[4][64];

    int tid = threadIdx.x;
    int lane = tid & 63, w = tid >> 6;
    int ln = lane & 15, quad = lane >> 4;

    qks[tid] = qk[b * FD + tid];
    bsh[tid] = b0[tid];

    // ---- stage X (full K) : thread -> node tid>>2, k-range (tid&3)*32..+32 ----
    {
        int node_s = tid >> 2, ks = (tid & 3) * 32;
        const float* Xr = X + (size_t)(off + n0 + node_s) * IN_D + ks;
        float xv[32];
        if (node_s < nvalid) {
#pragma unroll
            for (int q2 = 0; q2 < 8; q2++) {
                float4 v = ((const float4*)Xr)[q2];
                xv[q2 * 4 + 0] = v.x; xv[q2 * 4 + 1] = v.y;
                xv[q2 * 4 + 2] = v.z; xv[q2 * 4 + 3] = v.w;
            }
        } else {
#pragma unroll
            for (int q2 = 0; q2 < 32; q2++) xv[q2] = 0.f;
        }
#pragma unroll
        for (int g = 0; g < 4; g++) {
            uint4 hq, lq;
            split2(xv[g * 8 + 0], xv[g * 8 + 1], hq.x, lq.x);
            split2(xv[g * 8 + 2], xv[g * 8 + 3], hq.y, lq.y);
            split2(xv[g * 8 + 4], xv[g * 8 + 5], hq.z, lq.z);
            split2(xv[g * 8 + 6], xv[g * 8 + 7], hq.w, lq.w);
            *(uint4*)&XsH[node_s * XKS + ks + g * 8] = hq;
            *(uint4*)&XsL[node_s * XKS + ks + g * 8] = lq;
        }
    }
    __syncthreads();

    f32x4 acc[4][4] = {};
#pragma unroll
    for (int kc = 0; kc < 4; kc++) {
        bf16x8 AH[4], AL[4], BH[4], BL[4];
#pragma unroll
        for (int i = 0; i < 4; i++) {
            AH[i] = *(const bf16x8*)&XsH[(16 * i + ln) * XKS + kc * 32 + quad * 8];
            AL[i] = *(const bf16x8*)&XsL[(16 * i + ln) * XKS + kc * 32 + quad * 8];
        }
#pragma unroll
        for (int j = 0; j < 4; j++) {
            int c = 64 * w + 16 * j + ln;
            size_t base = (size_t)(kc * 256 + c) * 32 + quad * 8;
            BH[j] = *(const bf16x8*)&W0sH[base];
            BL[j] = *(const bf16x8*)&W0sL[base];
        }
#pragma unroll
        for (int i = 0; i < 4; i++)
#pragma unroll
            for (int j = 0; j < 4; j++) {
                acc[i][j] = __builtin_amdgcn_mfma_f32_16x16x32_bf16(AH[i], BH[j], acc[i][j], 0, 0, 0);
                acc[i][j] = __builtin_amdgcn_mfma_f32_16x16x32_bf16(AH[i], BL[j], acc[i][j], 0, 0, 0);
                acc[i][j] = __builtin_amdgcn_mfma_f32_16x16x32_bf16(AL[i], BH[j], acc[i][j], 0, 0, 0);
            }
    }

    // ---- epilogue: bias+relu+mask -> score partials & column sums ----
    float sp[4][4];
    float cs[4] = {0.f, 0.f, 0.f, 0.f};
#pragma unroll
    for (int i = 0; i < 4; i++)
#pragma unroll
        for (int r = 0; r < 4; r++) sp[i][r] = 0.f;

#pragma unroll
    for (int i = 0; i < 4; i++)
#pragma unroll
        for (int j = 0; j < 4; j++) {
            int c = 64 * w + 16 * j + ln;
            float bb = bsh[c], qv = qks[c];
#pragma unroll
            for (int r = 0; r < 4; r++) {
                int node = 16 * i + 4 * quad + r;
                float h = acc[i][j][r] + bb;
                h = (h > 0.f && node < nvalid) ? h : 0.f;
                sp[i][r] = fmaf(h, qv, sp[i][r]);
                cs[j] += h;
            }
        }
    // reduce score partials over ln (16 cols) in-wave
#pragma unroll
    for (int i = 0; i < 4; i++)
#pragma unroll
        for (int r = 0; r < 4; r++) {
            float s = sp[i][r];
            s += __shfl_xor(s, 1); s += __shfl_xor(s, 2);
            s += __shfl_xor(s, 4); s += __shfl_xor(s, 8);
            sp[i][r] = s;
        }
    if (ln == 0) {
#pragma unroll
        for (int i = 0; i < 4; i++)
#pragma unroll
            for (int r = 0; r < 4; r++)
                red[w][16 * i + 4 * quad + r] = sp[i][r];
    }
    // hsum: reduce over quads (nodes), one atomic per col
#pragma unroll
    for (int j = 0; j < 4; j++) {
        float s = cs[j];
        s += __shfl_xor(s, 16); s += __shfl_xor(s, 32);
        if (quad == 0) atomicAdd(&hsum[b * FD + 64 * w + 16 * j + ln], s);
    }
    __syncthreads();
    if (tid < 64 && tid < nvalid)
        scores[off + n0 + tid] = red[0][tid] + red[1][tid] + red[2][tid] + red[3][tid];
}

// ---------------------------------------------------------------------------
// K2: per-graph softmax stats + w_b = (hsum_b @ Wv + len*bv) @ Wo  (R0 verbatim)
// ---------------------------------------------------------------------------
__global__ __launch_bounds__(1024) void k_graph(
    const float* __restrict__ scores, const float* __restrict__ hsum,
    const float* __restrict__ Wv, const float* __restrict__ bv,
    const float* __restrict__ Wo, const int* __restrict__ offsets,
    float* __restrict__ wvec, float* __restrict__ smax, float* __restrict__ dinv)
{
    int b = blockIdx.x, tid = threadIdx.x;
    int t = tid & 255, g = tid >> 8;
    int off = offsets[b], len = offsets[b + 1] - off;
    __shared__ float redm[16], reds[16];
    __shared__ float hs[FD], vs[FD];
    __shared__ float part[4][FD];

    float m = -INFINITY;
    for (int i = tid; i < len; i += 1024) m = fmaxf(m, scores[off + i]);
    for (int d = 1; d < 64; d <<= 1) m = fmaxf(m, __shfl_xor(m, d));
    if ((tid & 63) == 0) redm[tid >> 6] = m;
    __syncthreads();
    m = -INFINITY;
#pragma unroll
    for (int k = 0; k < 16; k++) m = fmaxf(m, redm[k]);

    float s = 0.f;
    for (int i = tid; i < len; i += 1024) s += expf(scores[off + i] - m);
    for (int d = 1; d < 64; d <<= 1) s += __shfl_xor(s, d);
    if ((tid & 63) == 0) reds[tid >> 6] = s;
    if (g == 0) hs[t] = hsum[b * FD + t];
    __syncthreads();
    s = 0.f;
#pragma unroll
    for (int k = 0; k < 16; k++) s += reds[k];

    float acc = (g == 0) ? (float)len * bv[t] : 0.f;
    for (int f = 64 * g; f < 64 * g + 64; f++) acc = fmaf(hs[f], Wv[f * FD + t], acc);
    part[g][t] = acc;
    __syncthreads();
    if (g == 0) vs[t] = part[0][t] + part[1][t] + part[2][t] + part[3][t];
    __syncthreads();
    float a2 = 0.f;
    for (int f = 64 * g; f < 64 * g + 64; f++) a2 = fmaf(vs[f], Wo[f * HID + t], a2);
    part[g][t] = a2;
    __syncthreads();
    if (g == 0) wvec[b * HID + t] = part[0][t] + part[1][t] + part[2][t] + part[3][t];
    if (tid == 0) { smax[b] = m; dinv[b] = 1.0f / s; }
}

// ---------------------------------------------------------------------------
// K3: bf16x3 MFMA fin v2 (R6 verbatim): K-TILED Z (2 halves of 128) ->
// LDS 37.6 KB -> 4 blocks/CU.  Z regenerated from registers per half.
// ---------------------------------------------------------------------------
__global__ __launch_bounds__(256, 4) void k_fin_mfma(
    const float* __restrict__ scores, const float* __restrict__ wvec,
    const float* __restrict__ bo,
    const unsigned short* __restrict__ W2sH, const unsigned short* __restrict__ W2sL,
    const float* __restrict__ b2, const float* __restrict__ smax,
    const float* __restrict__ dinv, const int* __restrict__ offsets,
    float* __restrict__ Y)
{
    int b = blockIdx.y;
    int off = offsets[b], len = offsets[b + 1] - off;
    int n0 = blockIdx.x * 64;
    if (n0 >= len) return;
    int nvalid = min(64, len - n0);

    int tid = threadIdx.x;
    int lane = tid & 63, w = tid >> 6;
    int ln = lane & 15, quad = lane >> 4;

    __shared__ __align__(16) unsigned short ZsH[64 * XKS], ZsL[64 * XKS]; // 2x17408 B
    __shared__ float ps[64];
    __shared__ float wsh[HID];
    __shared__ float bosh[HID];
    __shared__ float b2sh[OUT_D];

    wsh[tid] = wvec[b * HID + tid];
    bosh[tid] = bo[tid];
    if (tid < OUT_D) b2sh[tid] = b2[tid];
    if (tid < 64) {
        float p = 0.f;
        if (tid < nvalid) p = expf(scores[off + n0 + tid] - smax[b]) * dinv[b];
        ps[tid] = p;
    }
    __syncthreads();

    f32x4 acc[4][2] = {};
    int node_s = tid >> 2, ks = (tid & 3) * 32;   // staging role (local k in half)

#pragma unroll
    for (int h = 0; h < 2; h++) {
        if (h) __syncthreads();   // protect LDS overwrite vs previous MFMA reads
        // ---- generate Z half [64 nodes][128 k]: k_global = h*128 + local ----
        {
            float pn = ps[node_s];
            int kg0 = h * 128 + ks;
#pragma unroll
            for (int g = 0; g < 4; g++) {
                uint4 hq, lq;
                int kb = kg0 + g * 8;
                float z0, z1;
                z0 = fmaxf(fmaf(pn, wsh[kb + 0], bosh[kb + 0]), 0.f);
                z1 = fmaxf(fmaf(pn, wsh[kb + 1], bosh[kb + 1]), 0.f);
                split2(z0, z1, hq.x, lq.x);
                z0 = fmaxf(fmaf(pn, wsh[kb + 2], bosh[kb + 2]), 0.f);
                z1 = fmaxf(fmaf(pn, wsh[kb + 3], bosh[kb + 3]), 0.f);
                split2(z0, z1, hq.y, lq.y);
                z0 = fmaxf(fmaf(pn, wsh[kb + 4], bosh[kb + 4]), 0.f);
                z1 = fmaxf(fmaf(pn, wsh[kb + 5], bosh[kb + 5]), 0.f);
                split2(z0, z1, hq.z, lq.z);
                z0 = fmaxf(fmaf(pn, wsh[kb + 6], bosh[kb + 6]), 0.f);
                z1 = fmaxf(fmaf(pn, wsh[kb + 7], bosh[kb + 7]), 0.f);
                split2(z0, z1, hq.w, lq.w);
                *(uint4*)&ZsH[node_s * XKS + ks + g * 8] = hq;
                *(uint4*)&ZsL[node_s * XKS + ks + g * 8] = lq;
            }
        }
        __syncthreads();

        // ---- MFMA over this half: kc_local 0..3, kc_global = h*4+kc ----
#pragma unroll
        for (int kc = 0; kc < 4; kc++) {
            bf16x8 AH[4], AL[4];
#pragma unroll
            for (int i = 0; i < 4; i++) {
                AH[i] = *(const bf16x8*)&ZsH[(16 * i + ln) * XKS + kc * 32 + quad * 8];
                AL[i] = *(const bf16x8*)&ZsL[(16 * i + ln) * XKS + kc * 32 + quad * 8];
            }
#pragma unroll
            for (int j = 0; j < 2; j++) {
                int c = 32 * w + 16 * j + ln;
                size_t base = (size_t)((h * 4 + kc) * 128 + c) * 32 + quad * 8;
                bf16x8 BH = *(const bf16x8*)&W2sH[base];
                bf16x8 BL = *(const bf16x8*)&W2sL[base];
#pragma unroll
                for (int i = 0; i < 4; i++) {
                    acc[i][j] = __builtin_amdgcn_mfma_f32_16x16x32_bf16(AH[i], BH, acc[i][j], 0, 0, 0);
                    acc[i][j] = __builtin_amdgcn_mfma_f32_16x16x32_bf16(AH[i], BL, acc[i][j], 0, 0, 0);
                    acc[i][j] = __builtin_amdgcn_mfma_f32_16x16x32_bf16(AL[i], BH, acc[i][j], 0, 0, 0);
                }
            }
        }
    }

    // ---- epilogue: + b2, masked store ----
#pragma unroll
    for (int i = 0; i < 4; i++)
#pragma unroll
        for (int j = 0; j < 2; j++) {
            int c = 32 * w + 16 * j + ln;
            float bb = b2sh[c];
#pragma unroll
            for (int r = 0; r < 4; r++) {
                int node = 16 * i + 4 * quad + r;
                if (node < nvalid)
                    Y[(size_t)(off + n0 + node) * OUT_D + c] = acc[i][j][r] + bb;
            }
        }
}

// ---------------------------------------------------------------------------
extern "C" void kernel_launch(void* const* d_in, const int* in_sizes, int n_in,
                              void* d_out, int out_size, void* d_ws, size_t ws_size,
                              hipStream_t stream)
{
    const float* X        = (const float*)d_in[0];
    const float* text_emb = (const float*)d_in[1];
    const int*   lens     = (const int*)d_in[2];
    const float* W0       = (const float*)d_in[3];
    const float* b0       = (const float*)d_in[4];
    const float* Wq       = (const float*)d_in[5];
    const float* bq       = (const float*)d_in[6];
    const float* Wk       = (const float*)d_in[7];
    // d_in[8] = bk : softmax-invariant, unused
    const float* Wv       = (const float*)d_in[9];
    const float* bv       = (const float*)d_in[10];
    const float* Wo       = (const float*)d_in[11];
    const float* bo       = (const float*)d_in[12];
    const float* W2       = (const float*)d_in[13];
    const float* b2       = (const float*)d_in[14];
    float* Y = (float*)d_out;

    char* base = (char*)d_ws;
    size_t o = 0;
    int*   offsets = (int*)(base + o);            o += 1088;
    float* qkbuf   = (float*)(base + o);          o += 262144;
    float* wvecb   = (float*)(base + o);          o += 262144;
    float* smaxb   = (float*)(base + o);          o += 1024;
    float* dinvb   = (float*)(base + o);          o += 1024;
    float* hsum    = (float*)(base + o);          o += 262144;
    float* scores  = (float*)(base + o);          o += 262144;
    unsigned short* W0sH = (unsigned short*)(base + o); o += 65536;
    unsigned short* W0sL = (unsigned short*)(base + o); o += 65536;
    unsigned short* W2sH = (unsigned short*)(base + o); o += 65536;
    unsigned short* W2sL = (unsigned short*)(base + o); o += 65536;

    k_prepA<<<265, 256, 0, stream>>>(text_emb, Wq, bq, Wk, W0, W2, lens,
                                     qkbuf, offsets, hsum, W0sH, W0sL, W2sH, W2sL);
    k_l0_mfma<<<dim3(6, B_G), 256, 0, stream>>>(X, W0sH, W0sL, b0, qkbuf, offsets, scores, hsum);
    k_graph<<<B_G, 1024, 0, stream>>>(scores, hsum, Wv, bv, Wo, offsets, wvecb, smaxb, dinvb);
    k_fin_mfma<<<dim3(6, B_G), 256, 0, stream>>>(scores, wvecb, bo, W2sH, W2sL, b2, smaxb, dinvb, offsets, Y);
}

// Round 9
// 186.326 us; speedup vs baseline: 1.8645x; 1.0186x over previous
//
#include <hip/hip_runtime.h>
#include <math.h>

#define B_G   256
#define IN_D  128
#define FD    256
#define HID   256
#define OUT_D 128
#define TXT   512
#define XKS   136   // X LDS k-stride (ushorts): 272 B/row, 16B-aligned, <=2-way bank
#define ZKS   72    // Z LDS k-stride (ushorts) for K=64 quarter: 144 B/row, 16B-aligned,
                    // bank shift 4/row -> <=2-way conflict on A-frag b128 reads

typedef short bf16x8 __attribute__((ext_vector_type(8)));
typedef float f32x4  __attribute__((ext_vector_type(4)));

// ---------------------------------------------------------------------------
// bf16 split helpers (RNE)
// ---------------------------------------------------------------------------
__device__ __forceinline__ unsigned bf_rne(float x) {
    unsigned u = __float_as_uint(x);
    u += 0x7fffu + ((u >> 16) & 1u);
    return u >> 16;
}
__device__ __forceinline__ float bf_to_f(unsigned h) {
    return __uint_as_float(h << 16);
}
__device__ __forceinline__ void split2(float a0, float a1, unsigned& hp, unsigned& lp) {
    unsigned h0 = bf_rne(a0), h1 = bf_rne(a1);
    float r0 = a0 - bf_to_f(h0), r1 = a1 - bf_to_f(h1);
    hp = h0 | (h1 << 16);
    lp = bf_rne(r0) | (bf_rne(r1) << 16);
}

// ---------------------------------------------------------------------------
// Kernel A (grid 265): fused prep.  (R0 verbatim)
// ---------------------------------------------------------------------------
__global__ __launch_bounds__(256) void k_prepA(
    const float* __restrict__ text_emb, const float* __restrict__ Wq,
    const float* __restrict__ bq, const float* __restrict__ Wk,
    const float* __restrict__ W0, const float* __restrict__ W2,
    const int* __restrict__ lens,
    float* __restrict__ qk, int* __restrict__ offsets, float* __restrict__ hsum,
    unsigned short* __restrict__ W0sH, unsigned short* __restrict__ W0sL,
    unsigned short* __restrict__ W2sH, unsigned short* __restrict__ W2sL)
{
    int blk = blockIdx.x, t = threadIdx.x;
    __shared__ float te[TXT];
    __shared__ float q[FD];
    __shared__ int   sc[B_G];

    if (blk < 256) {
        int b = blk;
        hsum[b * FD + t] = 0.f;
        for (int i = t; i < TXT; i += 256) te[i] = text_emb[(size_t)b * TXT + i];
        __syncthreads();
        float acc = bq[t];
        for (int k = 0; k < TXT; k++) acc = fmaf(te[k], Wq[k * FD + t], acc);
        q[t] = acc;
        __syncthreads();
        float a2 = 0.f;
        for (int f = 0; f < FD; f++) a2 = fmaf(Wk[t * FD + f], q[f], a2);
        qk[b * FD + t] = a2;
    } else if (blk < 264) {
        int e = (blk - 256) * 256 + t;   // 0..2047
        if (e < 1024) {
            int kc = e >> 8, c = e & 255;
            size_t base = (size_t)(kc * 256 + c) * 32;
            for (int kk = 0; kk < 32; kk++) {
                float v = W0[(size_t)(kc * 32 + kk) * FD + c];
                unsigned h = bf_rne(v);
                float r = v - bf_to_f(h);
                W0sH[base + kk] = (unsigned short)h;
                W0sL[base + kk] = (unsigned short)bf_rne(r);
            }
        } else {
            int e2 = e - 1024;
            int kc = e2 >> 7, c = e2 & 127;
            size_t base = (size_t)(kc * 128 + c) * 32;
            for (int kk = 0; kk < 32; kk++) {
                float v = W2[(size_t)(kc * 32 + kk) * OUT_D + c];
                unsigned h = bf_rne(v);
                float r = v - bf_to_f(h);
                W2sH[base + kk] = (unsigned short)h;
                W2sL[base + kk] = (unsigned short)bf_rne(r);
            }
        }
    } else {
        // parallel inclusive scan of lens (256 elements, 8 steps)
        sc[t] = lens[t];
        __syncthreads();
        for (int d = 1; d < 256; d <<= 1) {
            int v = (t >= d) ? sc[t - d] : 0;
            __syncthreads();
            sc[t] += v;
            __syncthreads();
        }
        offsets[t + 1] = sc[t];
        if (t == 0) offsets[0] = 0;
    }
}

// ---------------------------------------------------------------------------
// K1: bf16x3 MFMA.  Body = R0 v1 verbatim (fastest measured); ONLY change:
// __launch_bounds__(256,3) -> 3 blocks/CU (LDS 37.9*3=113.7<=160 KB; VGPR
// cap 170 >= ~150 hand-counted peak, so no spill / no load restructure).
// ---------------------------------------------------------------------------
__global__ __launch_bounds__(256, 3) void k_l0_mfma(
    const float* __restrict__ X,
    const unsigned short* __restrict__ W0sH, const unsigned short* __restrict__ W0sL,
    const float* __restrict__ b0, const float* __restrict__ qk,
    const int* __restrict__ offsets,
    float* __restrict__ scores, float* __restrict__ hsum)
{
    int b = blockIdx.y;
    int off = offsets[b], len = offsets[b + 1] - off;
    int n0 = blockIdx.x * 64;
    if (n0 >= len) return;
    int nvalid = min(64, len - n0);

    __shared__ __align__(16) unsigned short XsH[64 * XKS], XsL[64 * XKS]; // 2x17408 B
    __shared__ float qks[FD];
    __shared__ float bsh[FD];
    __shared__ float red[4][64];

    int tid = threadIdx.x;
    int lane = tid & 63, w = tid >> 6;
    int ln = lane & 15, quad = lane >> 4;

    qks[tid] = qk[b * FD + tid];
    bsh[tid] = b0[tid];

    // ---- stage X (full K) : thread -> node tid>>2, k-range (tid&3)*32..+32 ----
    {
        int node_s = tid >> 2, ks = (tid & 3) * 32;
        const float* Xr = X + (size_t)(off + n0 + node_s) * IN_D + ks;
        float xv[32];
        if (node_s < nvalid) {
#pragma unroll
            for (int q2 = 0; q2 < 8; q2++) {
                float4 v = ((const float4*)Xr)[q2];
                xv[q2 * 4 + 0] = v.x; xv[q2 * 4 + 1] = v.y;
                xv[q2 * 4 + 2] = v.z; xv[q2 * 4 + 3] = v.w;
            }
        } else {
#pragma unroll
            for (int q2 = 0; q2 < 32; q2++) xv[q2] = 0.f;
        }
#pragma unroll
        for (int g = 0; g < 4; g++) {
            uint4 hq, lq;
            split2(xv[g * 8 + 0], xv[g * 8 + 1], hq.x, lq.x);
            split2(xv[g * 8 + 2], xv[g * 8 + 3], hq.y, lq.y);
            split2(xv[g * 8 + 4], xv[g * 8 + 5], hq.z, lq.z);
            split2(xv[g * 8 + 6], xv[g * 8 + 7], hq.w, lq.w);
            *(uint4*)&XsH[node_s * XKS + ks + g * 8] = hq;
            *(uint4*)&XsL[node_s * XKS + ks + g * 8] = lq;
        }
    }
    __syncthreads();

    f32x4 acc[4][4] = {};
#pragma unroll
    for (int kc = 0; kc < 4; kc++) {
        bf16x8 AH[4], AL[4], BH[4], BL[4];
#pragma unroll
        for (int i = 0; i < 4; i++) {
            AH[i] = *(const bf16x8*)&XsH[(16 * i + ln) * XKS + kc * 32 + quad * 8];
            AL[i] = *(const bf16x8*)&XsL[(16 * i + ln) * XKS + kc * 32 + quad * 8];
        }
#pragma unroll
        for (int j = 0; j < 4; j++) {
            int c = 64 * w + 16 * j + ln;
            size_t base = (size_t)(kc * 256 + c) * 32 + quad * 8;
            BH[j] = *(const bf16x8*)&W0sH[base];
            BL[j] = *(const bf16x8*)&W0sL[base];
        }
#pragma unroll
        for (int i = 0; i < 4; i++)
#pragma unroll
            for (int j = 0; j < 4; j++) {
                acc[i][j] = __builtin_amdgcn_mfma_f32_16x16x32_bf16(AH[i], BH[j], acc[i][j], 0, 0, 0);
                acc[i][j] = __builtin_amdgcn_mfma_f32_16x16x32_bf16(AH[i], BL[j], acc[i][j], 0, 0, 0);
                acc[i][j] = __builtin_amdgcn_mfma_f32_16x16x32_bf16(AL[i], BH[j], acc[i][j], 0, 0, 0);
            }
    }

    // ---- epilogue: bias+relu+mask -> score partials & column sums ----
    float sp[4][4];
    float cs[4] = {0.f, 0.f, 0.f, 0.f};
#pragma unroll
    for (int i = 0; i < 4; i++)
#pragma unroll
        for (int r = 0; r < 4; r++) sp[i][r] = 0.f;

#pragma unroll
    for (int i = 0; i < 4; i++)
#pragma unroll
        for (int j = 0; j < 4; j++) {
            int c = 64 * w + 16 * j + ln;
            float bb = bsh[c], qv = qks[c];
#pragma unroll
            for (int r = 0; r < 4; r++) {
                int node = 16 * i + 4 * quad + r;
                float h = acc[i][j][r] + bb;
                h = (h > 0.f && node < nvalid) ? h : 0.f;
                sp[i][r] = fmaf(h, qv, sp[i][r]);
                cs[j] += h;
            }
        }
    // reduce score partials over ln (16 cols) in-wave
#pragma unroll
    for (int i = 0; i < 4; i++)
#pragma unroll
        for (int r = 0; r < 4; r++) {
            float s = sp[i][r];
            s += __shfl_xor(s, 1); s += __shfl_xor(s, 2);
            s += __shfl_xor(s, 4); s += __shfl_xor(s, 8);
            sp[i][r] = s;
        }
    if (ln == 0) {
#pragma unroll
        for (int i = 0; i < 4; i++)
#pragma unroll
            for (int r = 0; r < 4; r++)
                red[w][16 * i + 4 * quad + r] = sp[i][r];
    }
    // hsum: reduce over quads (nodes), one atomic per col
#pragma unroll
    for (int j = 0; j < 4; j++) {
        float s = cs[j];
        s += __shfl_xor(s, 16); s += __shfl_xor(s, 32);
        if (quad == 0) atomicAdd(&hsum[b * FD + 64 * w + 16 * j + ln], s);
    }
    __syncthreads();
    if (tid < 64 && tid < nvalid)
        scores[off + n0 + tid] = red[0][tid] + red[1][tid] + red[2][tid] + red[3][tid];
}

// ---------------------------------------------------------------------------
// K2: per-graph softmax stats + w_b = (hsum_b @ Wv + len*bv) @ Wo  (R0 verbatim)
// ---------------------------------------------------------------------------
__global__ __launch_bounds__(1024) void k_graph(
    const float* __restrict__ scores, const float* __restrict__ hsum,
    const float* __restrict__ Wv, const float* __restrict__ bv,
    const float* __restrict__ Wo, const int* __restrict__ offsets,
    float* __restrict__ wvec, float* __restrict__ smax, float* __restrict__ dinv)
{
    int b = blockIdx.x, tid = threadIdx.x;
    int t = tid & 255, g = tid >> 8;
    int off = offsets[b], len = offsets[b + 1] - off;
    __shared__ float redm[16], reds[16];
    __shared__ float hs[FD], vs[FD];
    __shared__ float part[4][FD];

    float m = -INFINITY;
    for (int i = tid; i < len; i += 1024) m = fmaxf(m, scores[off + i]);
    for (int d = 1; d < 64; d <<= 1) m = fmaxf(m, __shfl_xor(m, d));
    if ((tid & 63) == 0) redm[tid >> 6] = m;
    __syncthreads();
    m = -INFINITY;
#pragma unroll
    for (int k = 0; k < 16; k++) m = fmaxf(m, redm[k]);

    float s = 0.f;
    for (int i = tid; i < len; i += 1024) s += expf(scores[off + i] - m);
    for (int d = 1; d < 64; d <<= 1) s += __shfl_xor(s, d);
    if ((tid & 63) == 0) reds[tid >> 6] = s;
    if (g == 0) hs[t] = hsum[b * FD + t];
    __syncthreads();
    s = 0.f;
#pragma unroll
    for (int k = 0; k < 16; k++) s += reds[k];

    float acc = (g == 0) ? (float)len * bv[t] : 0.f;
    for (int f = 64 * g; f < 64 * g + 64; f++) acc = fmaf(hs[f], Wv[f * FD + t], acc);
    part[g][t] = acc;
    __syncthreads();
    if (g == 0) vs[t] = part[0][t] + part[1][t] + part[2][t] + part[3][t];
    __syncthreads();
    float a2 = 0.f;
    for (int f = 64 * g; f < 64 * g + 64; f++) a2 = fmaf(vs[f], Wo[f * HID + t], a2);
    part[g][t] = a2;
    __syncthreads();
    if (g == 0) wvec[b * HID + t] = part[0][t] + part[1][t] + part[2][t] + part[3][t];
    if (tid == 0) { smax[b] = m; dinv[b] = 1.0f / s; }
}

// ---------------------------------------------------------------------------
// K3: bf16x3 MFMA fin v3: K-QUARTER Z staging (4 stages of K=64) ->
// LDS ~21 KB -> 5 blocks/CU (__launch_bounds__(256,5), VGPR cap 102 >= 88).
// Z-gen wsh/bosh reads vectorized to float4 (4x fewer LDS instrs).
// ---------------------------------------------------------------------------
__global__ __launch_bounds__(256, 5) void k_fin_mfma(
    const float* __restrict__ scores, const float* __restrict__ wvec,
    const float* __restrict__ bo,
    const unsigned short* __restrict__ W2sH, const unsigned short* __restrict__ W2sL,
    const float* __restrict__ b2, const float* __restrict__ smax,
    const float* __restrict__ dinv, const int* __restrict__ offsets,
    float* __restrict__ Y)
{
    int b = blockIdx.y;
    int off = offsets[b], len = offsets[b + 1] - off;
    int n0 = blockIdx.x * 64;
    if (n0 >= len) return;
    int nvalid = min(64, len - n0);

    int tid = threadIdx.x;
    int lane = tid & 63, w = tid >> 6;
    int ln = lane & 15, quad = lane >> 4;

    __shared__ __align__(16) unsigned short ZsH[64 * ZKS], ZsL[64 * ZKS]; // 2x9216 B
    __shared__ float ps[64];
    __shared__ __align__(16) float wsh[HID];
    __shared__ __align__(16) float bosh[HID];
    __shared__ float b2sh[OUT_D];

    wsh[tid] = wvec[b * HID + tid];
    bosh[tid] = bo[tid];
    if (tid < OUT_D) b2sh[tid] = b2[tid];
    if (tid < 64) {
        float p = 0.f;
        if (tid < nvalid) p = expf(scores[off + n0 + tid] - smax[b]) * dinv[b];
        ps[tid] = p;
    }
    __syncthreads();

    f32x4 acc[4][2] = {};
    int node_s = tid >> 2, ks = (tid & 3) * 16;   // staging role: 16 k per thread

#pragma unroll
    for (int s = 0; s < 4; s++) {
        if (s) __syncthreads();   // protect LDS overwrite vs previous MFMA reads
        // ---- generate Z quarter [64 nodes][64 k]: k_global = s*64 + local ----
        {
            float pn = ps[node_s];
#pragma unroll
            for (int g = 0; g < 2; g++) {
                int kl = ks + g * 8;            // local k of this 8-group
                int kg = s * 64 + kl;           // global k
                float4 w4a = *(const float4*)&wsh[kg];
                float4 w4b = *(const float4*)&wsh[kg + 4];
                float4 b4a = *(const float4*)&bosh[kg];
                float4 b4b = *(const float4*)&bosh[kg + 4];
                uint4 hq, lq;
                float z0, z1;
                z0 = fmaxf(fmaf(pn, w4a.x, b4a.x), 0.f);
                z1 = fmaxf(fmaf(pn, w4a.y, b4a.y), 0.f);
                split2(z0, z1, hq.x, lq.x);
                z0 = fmaxf(fmaf(pn, w4a.z, b4a.z), 0.f);
                z1 = fmaxf(fmaf(pn, w4a.w, b4a.w), 0.f);
                split2(z0, z1, hq.y, lq.y);
                z0 = fmaxf(fmaf(pn, w4b.x, b4b.x), 0.f);
                z1 = fmaxf(fmaf(pn, w4b.y, b4b.y), 0.f);
                split2(z0, z1, hq.z, lq.z);
                z0 = fmaxf(fmaf(pn, w4b.z, b4b.z), 0.f);
                z1 = fmaxf(fmaf(pn, w4b.w, b4b.w), 0.f);
                split2(z0, z1, hq.w, lq.w);
                *(uint4*)&ZsH[node_s * ZKS + kl] = hq;
                *(uint4*)&ZsL[node_s * ZKS + kl] = lq;
            }
        }
        __syncthreads();

        // ---- MFMA over this quarter: kc_local 0..1, kc_global = s*2+kc ----
#pragma unroll
        for (int kc = 0; kc < 2; kc++) {
            bf16x8 AH[4], AL[4];
#pragma unroll
            for (int i = 0; i < 4; i++) {
                AH[i] = *(const bf16x8*)&ZsH[(16 * i + ln) * ZKS + kc * 32 + quad * 8];
                AL[i] = *(const bf16x8*)&ZsL[(16 * i + ln) * ZKS + kc * 32 + quad * 8];
            }
#pragma unroll
            for (int j = 0; j < 2; j++) {
                int c = 32 * w + 16 * j + ln;
                size_t base = (size_t)((s * 2 + kc) * 128 + c) * 32 + quad * 8;
                bf16x8 BH = *(const bf16x8*)&W2sH[base];
                bf16x8 BL = *(const bf16x8*)&W2sL[base];
#pragma unroll
                for (int i = 0; i < 4; i++) {
                    acc[i][j] = __builtin_amdgcn_mfma_f32_16x16x32_bf16(AH[i], BH, acc[i][j], 0, 0, 0);
                    acc[i][j] = __builtin_amdgcn_mfma_f32_16x16x32_bf16(AH[i], BL, acc[i][j], 0, 0, 0);
                    acc[i][j] = __builtin_amdgcn_mfma_f32_16x16x32_bf16(AL[i], BH, acc[i][j], 0, 0, 0);
                }
            }
        }
    }

    // ---- epilogue: + b2, masked store ----
#pragma unroll
    for (int i = 0; i < 4; i++)
#pragma unroll
        for (int j = 0; j < 2; j++) {
            int c = 32 * w + 16 * j + ln;
            float bb = b2sh[c];
#pragma unroll
            for (int r = 0; r < 4; r++) {
                int node = 16 * i + 4 * quad + r;
                if (node < nvalid)
                    Y[(size_t)(off + n0 + node) * OUT_D + c] = acc[i][j][r] + bb;
            }
        }
}

// ---------------------------------------------------------------------------
extern "C" void kernel_launch(void* const* d_in, const int* in_sizes, int n_in,
                              void* d_out, int out_size, void* d_ws, size_t ws_size,
                              hipStream_t stream)
{
    const float* X        = (const float*)d_in[0];
    const float* text_emb = (const float*)d_in[1];
    const int*   lens     = (const int*)d_in[2];
    const float* W0       = (const float*)d_in[3];
    const float* b0       = (const float*)d_in[4];
    const float* Wq       = (const float*)d_in[5];
    const float* bq       = (const float*)d_in[6];
    const float* Wk       = (const float*)d_in[7];
    // d_in[8] = bk : softmax-invariant, unused
    const float* Wv       = (const float*)d_in[9];
    const float* bv       = (const float*)d_in[10];
    const float* Wo       = (const float*)d_in[11];
    const float* bo       = (const float*)d_in[12];
    const float* W2       = (const float*)d_in[13];
    const float* b2       = (const float*)d_in[14];
    float* Y = (float*)d_out;

    char* base = (char*)d_ws;
    size_t o = 0;
    int*   offsets = (int*)(base + o);            o += 1088;
    float* qkbuf   = (float*)(base + o);          o += 262144;
    float* wvecb   = (float*)(base + o);          o += 262144;
    float* smaxb   = (float*)(base + o);          o += 1024;
    float* dinvb   = (float*)(base + o);          o += 1024;
    float* hsum    = (float*)(base + o);          o += 262144;
    float* scores  = (float*)(base + o);          o += 262144;
    unsigned short* W0sH = (unsigned short*)(base + o); o += 65536;
    unsigned short* W0sL = (unsigned short*)(base + o); o += 65536;
    unsigned short* W2sH = (unsigned short*)(base + o); o += 65536;
    unsigned short* W2sL = (unsigned short*)(base + o); o += 65536;

    k_prepA<<<265, 256, 0, stream>>>(text_emb, Wq, bq, Wk, W0, W2, lens,
                                     qkbuf, offsets, hsum, W0sH, W0sL, W2sH, W2sL);
    k_l0_mfma<<<dim3(6, B_G), 256, 0, stream>>>(X, W0sH, W0sL, b0, qkbuf, offsets, scores, hsum);
    k_graph<<<B_G, 1024, 0, stream>>>(scores, hsum, Wv, bv, Wo, offsets, wvecb, smaxb, dinvb);
    k_fin_mfma<<<dim3(6, B_G), 256, 0, stream>>>(scores, wvecb, bo, W2sH, W2sL, b2, smaxb, dinvb, offsets, Y);
}

// Round 10
// 185.438 us; speedup vs baseline: 1.8734x; 1.0048x over previous
//
#include <hip/hip_runtime.h>
#include <math.h>

#define B_G   256
#define IN_D  128
#define FD    256
#define HID   256
#define OUT_D 128
#define TXT   512
#define XKS   136   // X LDS k-stride (ushorts): 272 B/row, <=2-way bank on b128 reads
#define ZKS   72    // Z LDS k-stride (ushorts) for K=64 quarter staging (fin v3)
#define MKS   264   // k_mid LDS k-stride (ushorts) for K=256 rows: 528 B/row, <=2-way

typedef short bf16x8 __attribute__((ext_vector_type(8)));
typedef float f32x4  __attribute__((ext_vector_type(4)));

// ---------------------------------------------------------------------------
// bf16 split helpers (RNE)
// ---------------------------------------------------------------------------
__device__ __forceinline__ unsigned bf_rne(float x) {
    unsigned u = __float_as_uint(x);
    u += 0x7fffu + ((u >> 16) & 1u);
    return u >> 16;
}
__device__ __forceinline__ float bf_to_f(unsigned h) {
    return __uint_as_float(h << 16);
}
__device__ __forceinline__ void split2(float a0, float a1, unsigned& hp, unsigned& lp) {
    unsigned h0 = bf_rne(a0), h1 = bf_rne(a1);
    float r0 = a0 - bf_to_f(h0), r1 = a1 - bf_to_f(h1);
    hp = h0 | (h1 << 16);
    lp = bf_rne(r0) | (bf_rne(r1) << 16);
}

// ---------------------------------------------------------------------------
// Kernel A (grid 281): fused prep.
//  blocks 0..255  : q_b = te@Wq+bq ; qk_b = Wk@q_b ; zero hsum[b]
//  blocks 256..263: split W0 / W2   (fragment layout hi/lo)
//  blocks 264..271: split Wv        (WvS[kc=8][col=256][kk=32])
//  blocks 272..279: split Wo        (WoS[kc=8][col=256][kk=32])
//  block  280     : parallel scan of lens -> offsets
// ---------------------------------------------------------------------------
__global__ __launch_bounds__(256) void k_prepA(
    const float* __restrict__ text_emb, const float* __restrict__ Wq,
    const float* __restrict__ bq, const float* __restrict__ Wk,
    const float* __restrict__ W0, const float* __restrict__ W2,
    const float* __restrict__ Wv, const float* __restrict__ Wo,
    const int* __restrict__ lens,
    float* __restrict__ qk, int* __restrict__ offsets, float* __restrict__ hsum,
    unsigned short* __restrict__ W0sH, unsigned short* __restrict__ W0sL,
    unsigned short* __restrict__ W2sH, unsigned short* __restrict__ W2sL,
    unsigned short* __restrict__ WvsH, unsigned short* __restrict__ WvsL,
    unsigned short* __restrict__ WosH, unsigned short* __restrict__ WosL)
{
    int blk = blockIdx.x, t = threadIdx.x;
    __shared__ float te[TXT];
    __shared__ float q[FD];
    __shared__ int   sc[B_G];

    if (blk < 256) {
        int b = blk;
        hsum[b * FD + t] = 0.f;
        for (int i = t; i < TXT; i += 256) te[i] = text_emb[(size_t)b * TXT + i];
        __syncthreads();
        float acc = bq[t];
        for (int k = 0; k < TXT; k++) acc = fmaf(te[k], Wq[k * FD + t], acc);
        q[t] = acc;
        __syncthreads();
        float a2 = 0.f;
        for (int f = 0; f < FD; f++) a2 = fmaf(Wk[t * FD + f], q[f], a2);
        qk[b * FD + t] = a2;
    } else if (blk < 264) {
        int e = (blk - 256) * 256 + t;   // 0..2047
        if (e < 1024) {
            int kc = e >> 8, c = e & 255;
            size_t base = (size_t)(kc * 256 + c) * 32;
            for (int kk = 0; kk < 32; kk++) {
                float v = W0[(size_t)(kc * 32 + kk) * FD + c];
                unsigned h = bf_rne(v);
                float r = v - bf_to_f(h);
                W0sH[base + kk] = (unsigned short)h;
                W0sL[base + kk] = (unsigned short)bf_rne(r);
            }
        } else {
            int e2 = e - 1024;
            int kc = e2 >> 7, c = e2 & 127;
            size_t base = (size_t)(kc * 128 + c) * 32;
            for (int kk = 0; kk < 32; kk++) {
                float v = W2[(size_t)(kc * 32 + kk) * OUT_D + c];
                unsigned h = bf_rne(v);
                float r = v - bf_to_f(h);
                W2sH[base + kk] = (unsigned short)h;
                W2sL[base + kk] = (unsigned short)bf_rne(r);
            }
        }
    } else if (blk < 272) {
        int e = (blk - 264) * 256 + t;   // 0..2047: kc 0..7 x col 0..255
        int kc = e >> 8, c = e & 255;
        size_t base = (size_t)(kc * 256 + c) * 32;
        for (int kk = 0; kk < 32; kk++) {
            float v = Wv[(size_t)(kc * 32 + kk) * FD + c];
            unsigned h = bf_rne(v);
            float r = v - bf_to_f(h);
            WvsH[base + kk] = (unsigned short)h;
            WvsL[base + kk] = (unsigned short)bf_rne(r);
        }
    } else if (blk < 280) {
        int e = (blk - 272) * 256 + t;   // 0..2047
        int kc = e >> 8, c = e & 255;
        size_t base = (size_t)(kc * 256 + c) * 32;
        for (int kk = 0; kk < 32; kk++) {
            float v = Wo[(size_t)(kc * 32 + kk) * HID + c];
            unsigned h = bf_rne(v);
            float r = v - bf_to_f(h);
            WosH[base + kk] = (unsigned short)h;
            WosL[base + kk] = (unsigned short)bf_rne(r);
        }
    } else {
        // parallel inclusive scan of lens (256 elements, 8 steps)
        sc[t] = lens[t];
        __syncthreads();
        for (int d = 1; d < 256; d <<= 1) {
            int v = (t >= d) ? sc[t - d] : 0;
            __syncthreads();
            sc[t] += v;
            __syncthreads();
        }
        offsets[t + 1] = sc[t];
        if (t == 0) offsets[0] = 0;
    }
}

// ---------------------------------------------------------------------------
// K1: bf16x3 MFMA.  (R9 verbatim: R0 body + __launch_bounds__(256,3))
// ---------------------------------------------------------------------------
__global__ __launch_bounds__(256, 3) void k_l0_mfma(
    const float* __restrict__ X,
    const unsigned short* __restrict__ W0sH, const unsigned short* __restrict__ W0sL,
    const float* __restrict__ b0, const float* __restrict__ qk,
    const int* __restrict__ offsets,
    float* __restrict__ scores, float* __restrict__ hsum)
{
    int b = blockIdx.y;
    int off = offsets[b], len = offsets[b + 1] - off;
    int n0 = blockIdx.x * 64;
    if (n0 >= len) return;
    int nvalid = min(64, len - n0);

    __shared__ __align__(16) unsigned short XsH[64 * XKS], XsL[64 * XKS]; // 2x17408 B
    __shared__ float qks[FD];
    __shared__ float bsh[FD];
    __shared__ float red[4][64];

    int tid = threadIdx.x;
    int lane = tid & 63, w = tid >> 6;
    int ln = lane & 15, quad = lane >> 4;

    qks[tid] = qk[b * FD + tid];
    bsh[tid] = b0[tid];

    // ---- stage X (full K) : thread -> node tid>>2, k-range (tid&3)*32..+32 ----
    {
        int node_s = tid >> 2, ks = (tid & 3) * 32;
        const float* Xr = X + (size_t)(off + n0 + node_s) * IN_D + ks;
        float xv[32];
        if (node_s < nvalid) {
#pragma unroll
            for (int q2 = 0; q2 < 8; q2++) {
                float4 v = ((const float4*)Xr)[q2];
                xv[q2 * 4 + 0] = v.x; xv[q2 * 4 + 1] = v.y;
                xv[q2 * 4 + 2] = v.z; xv[q2 * 4 + 3] = v.w;
            }
        } else {
#pragma unroll
            for (int q2 = 0; q2 < 32; q2++) xv[q2] = 0.f;
        }
#pragma unroll
        for (int g = 0; g < 4; g++) {
            uint4 hq, lq;
            split2(xv[g * 8 + 0], xv[g * 8 + 1], hq.x, lq.x);
            split2(xv[g * 8 + 2], xv[g * 8 + 3], hq.y, lq.y);
            split2(xv[g * 8 + 4], xv[g * 8 + 5], hq.z, lq.z);
            split2(xv[g * 8 + 6], xv[g * 8 + 7], hq.w, lq.w);
            *(uint4*)&XsH[node_s * XKS + ks + g * 8] = hq;
            *(uint4*)&XsL[node_s * XKS + ks + g * 8] = lq;
        }
    }
    __syncthreads();

    f32x4 acc[4][4] = {};
#pragma unroll
    for (int kc = 0; kc < 4; kc++) {
        bf16x8 AH[4], AL[4], BH[4], BL[4];
#pragma unroll
        for (int i = 0; i < 4; i++) {
            AH[i] = *(const bf16x8*)&XsH[(16 * i + ln) * XKS + kc * 32 + quad * 8];
            AL[i] = *(const bf16x8*)&XsL[(16 * i + ln) * XKS + kc * 32 + quad * 8];
        }
#pragma unroll
        for (int j = 0; j < 4; j++) {
            int c = 64 * w + 16 * j + ln;
            size_t base = (size_t)(kc * 256 + c) * 32 + quad * 8;
            BH[j] = *(const bf16x8*)&W0sH[base];
            BL[j] = *(const bf16x8*)&W0sL[base];
        }
#pragma unroll
        for (int i = 0; i < 4; i++)
#pragma unroll
            for (int j = 0; j < 4; j++) {
                acc[i][j] = __builtin_amdgcn_mfma_f32_16x16x32_bf16(AH[i], BH[j], acc[i][j], 0, 0, 0);
                acc[i][j] = __builtin_amdgcn_mfma_f32_16x16x32_bf16(AH[i], BL[j], acc[i][j], 0, 0, 0);
                acc[i][j] = __builtin_amdgcn_mfma_f32_16x16x32_bf16(AL[i], BH[j], acc[i][j], 0, 0, 0);
            }
    }

    // ---- epilogue: bias+relu+mask -> score partials & column sums ----
    float sp[4][4];
    float cs[4] = {0.f, 0.f, 0.f, 0.f};
#pragma unroll
    for (int i = 0; i < 4; i++)
#pragma unroll
        for (int r = 0; r < 4; r++) sp[i][r] = 0.f;

#pragma unroll
    for (int i = 0; i < 4; i++)
#pragma unroll
        for (int j = 0; j < 4; j++) {
            int c = 64 * w + 16 * j + ln;
            float bb = bsh[c], qv = qks[c];
#pragma unroll
            for (int r = 0; r < 4; r++) {
                int node = 16 * i + 4 * quad + r;
                float h = acc[i][j][r] + bb;
                h = (h > 0.f && node < nvalid) ? h : 0.f;
                sp[i][r] = fmaf(h, qv, sp[i][r]);
                cs[j] += h;
            }
        }
    // reduce score partials over ln (16 cols) in-wave
#pragma unroll
    for (int i = 0; i < 4; i++)
#pragma unroll
        for (int r = 0; r < 4; r++) {
            float s = sp[i][r];
            s += __shfl_xor(s, 1); s += __shfl_xor(s, 2);
            s += __shfl_xor(s, 4); s += __shfl_xor(s, 8);
            sp[i][r] = s;
        }
    if (ln == 0) {
#pragma unroll
        for (int i = 0; i < 4; i++)
#pragma unroll
            for (int r = 0; r < 4; r++)
                red[w][16 * i + 4 * quad + r] = sp[i][r];
    }
    // hsum: reduce over quads (nodes), one atomic per col
#pragma unroll
    for (int j = 0; j < 4; j++) {
        float s = cs[j];
        s += __shfl_xor(s, 16); s += __shfl_xor(s, 32);
        if (quad == 0) atomicAdd(&hsum[b * FD + 64 * w + 16 * j + ln], s);
    }
    __syncthreads();
    if (tid < 64 && tid < nvalid)
        scores[off + n0 + tid] = red[0][tid] + red[1][tid] + red[2][tid] + red[3][tid];
}

// ---------------------------------------------------------------------------
// K2 (NEW): k_mid — grid 272 x 256 threads.
//  blocks 0..15 : batched wvec GEMM pipeline, 16 graphs (rows) per block:
//                 Hs(16x256,bf16x4 split) @ WvS -> +len*bv -> split -> @ WoS.
//                 Replaces 256 per-graph GEMV chains (128 MB L2 churn -> ~2 MB).
//  blocks 16..271: per-graph softmax stats (smax, dinv).
// ---------------------------------------------------------------------------
__global__ __launch_bounds__(256) void k_mid(
    const float* __restrict__ scores, const float* __restrict__ hsum,
    const unsigned short* __restrict__ WvsH, const unsigned short* __restrict__ WvsL,
    const unsigned short* __restrict__ WosH, const unsigned short* __restrict__ WosL,
    const float* __restrict__ bv, const int* __restrict__ offsets,
    float* __restrict__ wvec, float* __restrict__ smax, float* __restrict__ dinv)
{
    int blk = blockIdx.x, tid = threadIdx.x;
    int lane = tid & 63, w = tid >> 6;

    __shared__ __align__(16) unsigned short AsH[16 * MKS], AsL[16 * MKS]; // 2x8448 B
    __shared__ float lensh[16];
    __shared__ float redm[4], reds[4];

    if (blk >= 16) {
        // ---- per-graph softmax stats ----
        int b = blk - 16;
        int off = offsets[b], len = offsets[b + 1] - off;
        float s0 = (tid < len) ? scores[off + tid] : -INFINITY;
        float s1 = (tid + 256 < len) ? scores[off + tid + 256] : -INFINITY;
        float m = fmaxf(s0, s1);
#pragma unroll
        for (int d = 1; d < 64; d <<= 1) m = fmaxf(m, __shfl_xor(m, d));
        if (lane == 0) redm[w] = m;
        __syncthreads();
        m = fmaxf(fmaxf(redm[0], redm[1]), fmaxf(redm[2], redm[3]));
        float e = ((tid < len) ? expf(s0 - m) : 0.f)
                + ((tid + 256 < len) ? expf(s1 - m) : 0.f);
#pragma unroll
        for (int d = 1; d < 64; d <<= 1) e += __shfl_xor(e, d);
        if (lane == 0) reds[w] = e;
        __syncthreads();
        float s = reds[0] + reds[1] + reds[2] + reds[3];
        if (tid == 0) { smax[b] = m; dinv[b] = 1.0f / s; }
        return;
    }

    // ---- GEMM block: graphs g0..g0+15 ----
    int g0 = blk * 16;
    int ln = lane & 15, quad = lane >> 4;

    if (tid < 16) lensh[tid] = (float)(offsets[g0 + tid + 1] - offsets[g0 + tid]);

    // stage hsum tile (16 rows x K=256): thread -> row tid>>4, ks (tid&15)*16
    {
        int row = tid >> 4, ks = (tid & 15) * 16;
        const float4* H4 = (const float4*)(hsum + (size_t)(g0 + row) * FD + ks);
#pragma unroll
        for (int g = 0; g < 2; g++) {
            float4 a = H4[2 * g], c4 = H4[2 * g + 1];
            uint4 hq, lq;
            split2(a.x,  a.y,  hq.x, lq.x);
            split2(a.z,  a.w,  hq.y, lq.y);
            split2(c4.x, c4.y, hq.z, lq.z);
            split2(c4.z, c4.w, hq.w, lq.w);
            *(uint4*)&AsH[row * MKS + ks + g * 8] = hq;
            *(uint4*)&AsL[row * MKS + ks + g * 8] = lq;
        }
    }
    __syncthreads();

    // GEMM1: V = Hs @ Wv   (bf16x4: includes AL*BL for chained-GEMM accuracy)
    f32x4 acc[4] = {};
#pragma unroll
    for (int kc = 0; kc < 8; kc++) {
        bf16x8 AH = *(const bf16x8*)&AsH[ln * MKS + kc * 32 + quad * 8];
        bf16x8 AL = *(const bf16x8*)&AsL[ln * MKS + kc * 32 + quad * 8];
#pragma unroll
        for (int j = 0; j < 4; j++) {
            int c = 64 * w + 16 * j + ln;
            size_t base = (size_t)(kc * 256 + c) * 32 + quad * 8;
            bf16x8 BH = *(const bf16x8*)&WvsH[base];
            bf16x8 BL = *(const bf16x8*)&WvsL[base];
            acc[j] = __builtin_amdgcn_mfma_f32_16x16x32_bf16(AH, BH, acc[j], 0, 0, 0);
            acc[j] = __builtin_amdgcn_mfma_f32_16x16x32_bf16(AH, BL, acc[j], 0, 0, 0);
            acc[j] = __builtin_amdgcn_mfma_f32_16x16x32_bf16(AL, BH, acc[j], 0, 0, 0);
            acc[j] = __builtin_amdgcn_mfma_f32_16x16x32_bf16(AL, BL, acc[j], 0, 0, 0);
        }
    }
    __syncthreads();   // all waves done reading As before overwrite

    // epilogue1: V = acc + len*bv -> split back into As (reused as Vs)
#pragma unroll
    for (int j = 0; j < 4; j++) {
        int c = 64 * w + 16 * j + ln;
        float bvv = bv[c];
#pragma unroll
        for (int r = 0; r < 4; r++) {
            int row = 4 * quad + r;
            float v = acc[j][r] + lensh[row] * bvv;
            unsigned h = bf_rne(v);
            float res = v - bf_to_f(h);
            AsH[row * MKS + c] = (unsigned short)h;
            AsL[row * MKS + c] = (unsigned short)bf_rne(res);
        }
    }
    __syncthreads();

    // GEMM2: wvec = Vs @ Wo  (bf16x4)
    f32x4 acc2[4] = {};
#pragma unroll
    for (int kc = 0; kc < 8; kc++) {
        bf16x8 AH = *(const bf16x8*)&AsH[ln * MKS + kc * 32 + quad * 8];
        bf16x8 AL = *(const bf16x8*)&AsL[ln * MKS + kc * 32 + quad * 8];
#pragma unroll
        for (int j = 0; j < 4; j++) {
            int c = 64 * w + 16 * j + ln;
            size_t base = (size_t)(kc * 256 + c) * 32 + quad * 8;
            bf16x8 BH = *(const bf16x8*)&WosH[base];
            bf16x8 BL = *(const bf16x8*)&WosL[base];
            acc2[j] = __builtin_amdgcn_mfma_f32_16x16x32_bf16(AH, BH, acc2[j], 0, 0, 0);
            acc2[j] = __builtin_amdgcn_mfma_f32_16x16x32_bf16(AH, BL, acc2[j], 0, 0, 0);
            acc2[j] = __builtin_amdgcn_mfma_f32_16x16x32_bf16(AL, BH, acc2[j], 0, 0, 0);
            acc2[j] = __builtin_amdgcn_mfma_f32_16x16x32_bf16(AL, BL, acc2[j], 0, 0, 0);
        }
    }

    // write wvec
#pragma unroll
    for (int j = 0; j < 4; j++) {
        int c = 64 * w + 16 * j + ln;
#pragma unroll
        for (int r = 0; r < 4; r++) {
            int row = 4 * quad + r;
            wvec[(size_t)(g0 + row) * HID + c] = acc2[j][r];
        }
    }
}

// ---------------------------------------------------------------------------
// K3: bf16x3 MFMA fin v3 (R9 verbatim): K-quarter Z staging, 5 blocks/CU.
// ---------------------------------------------------------------------------
__global__ __launch_bounds__(256, 5) void k_fin_mfma(
    const float* __restrict__ scores, const float* __restrict__ wvec,
    const float* __restrict__ bo,
    const unsigned short* __restrict__ W2sH, const unsigned short* __restrict__ W2sL,
    const float* __restrict__ b2, const float* __restrict__ smax,
    const float* __restrict__ dinv, const int* __restrict__ offsets,
    float* __restrict__ Y)
{
    int b = blockIdx.y;
    int off = offsets[b], len = offsets[b + 1] - off;
    int n0 = blockIdx.x * 64;
    if (n0 >= len) return;
    int nvalid = min(64, len - n0);

    int tid = threadIdx.x;
    int lane = tid & 63, w = tid >> 6;
    int ln = lane & 15, quad = lane >> 4;

    __shared__ __align__(16) unsigned short ZsH[64 * ZKS], ZsL[64 * ZKS]; // 2x9216 B
    __shared__ float ps[64];
    __shared__ __align__(16) float wsh[HID];
    __shared__ __align__(16) float bosh[HID];
    __shared__ float b2sh[OUT_D];

    wsh[tid] = wvec[b * HID + tid];
    bosh[tid] = bo[tid];
    if (tid < OUT_D) b2sh[tid] = b2[tid];
    if (tid < 64) {
        float p = 0.f;
        if (tid < nvalid) p = expf(scores[off + n0 + tid] - smax[b]) * dinv[b];
        ps[tid] = p;
    }
    __syncthreads();

    f32x4 acc[4][2] = {};
    int node_s = tid >> 2, ks = (tid & 3) * 16;   // staging role: 16 k per thread

#pragma unroll
    for (int s = 0; s < 4; s++) {
        if (s) __syncthreads();   // protect LDS overwrite vs previous MFMA reads
        // ---- generate Z quarter [64 nodes][64 k]: k_global = s*64 + local ----
        {
            float pn = ps[node_s];
#pragma unroll
            for (int g = 0; g < 2; g++) {
                int kl = ks + g * 8;            // local k of this 8-group
                int kg = s * 64 + kl;           // global k
                float4 w4a = *(const float4*)&wsh[kg];
                float4 w4b = *(const float4*)&wsh[kg + 4];
                float4 b4a = *(const float4*)&bosh[kg];
                float4 b4b = *(const float4*)&bosh[kg + 4];
                uint4 hq, lq;
                float z0, z1;
                z0 = fmaxf(fmaf(pn, w4a.x, b4a.x), 0.f);
                z1 = fmaxf(fmaf(pn, w4a.y, b4a.y), 0.f);
                split2(z0, z1, hq.x, lq.x);
                z0 = fmaxf(fmaf(pn, w4a.z, b4a.z), 0.f);
                z1 = fmaxf(fmaf(pn, w4a.w, b4a.w), 0.f);
                split2(z0, z1, hq.y, lq.y);
                z0 = fmaxf(fmaf(pn, w4b.x, b4b.x), 0.f);
                z1 = fmaxf(fmaf(pn, w4b.y, b4b.y), 0.f);
                split2(z0, z1, hq.z, lq.z);
                z0 = fmaxf(fmaf(pn, w4b.z, b4b.z), 0.f);
                z1 = fmaxf(fmaf(pn, w4b.w, b4b.w), 0.f);
                split2(z0, z1, hq.w, lq.w);
                *(uint4*)&ZsH[node_s * ZKS + kl] = hq;
                *(uint4*)&ZsL[node_s * ZKS + kl] = lq;
            }
        }
        __syncthreads();

        // ---- MFMA over this quarter: kc_local 0..1, kc_global = s*2+kc ----
#pragma unroll
        for (int kc = 0; kc < 2; kc++) {
            bf16x8 AH[4], AL[4];
#pragma unroll
            for (int i = 0; i < 4; i++) {
                AH[i] = *(const bf16x8*)&ZsH[(16 * i + ln) * ZKS + kc * 32 + quad * 8];
                AL[i] = *(const bf16x8*)&ZsL[(16 * i + ln) * ZKS + kc * 32 + quad * 8];
            }
#pragma unroll
            for (int j = 0; j < 2; j++) {
                int c = 32 * w + 16 * j + ln;
                size_t base = (size_t)((s * 2 + kc) * 128 + c) * 32 + quad * 8;
                bf16x8 BH = *(const bf16x8*)&W2sH[base];
                bf16x8 BL = *(const bf16x8*)&W2sL[base];
#pragma unroll
                for (int i = 0; i < 4; i++) {
                    acc[i][j] = __builtin_amdgcn_mfma_f32_16x16x32_bf16(AH[i], BH, acc[i][j], 0, 0, 0);
                    acc[i][j] = __builtin_amdgcn_mfma_f32_16x16x32_bf16(AH[i], BL, acc[i][j], 0, 0, 0);
                    acc[i][j] = __builtin_amdgcn_mfma_f32_16x16x32_bf16(AL[i], BH, acc[i][j], 0, 0, 0);
                }
            }
        }
    }

    // ---- epilogue: + b2, masked store ----
#pragma unroll
    for (int i = 0; i < 4; i++)
#pragma unroll
        for (int j = 0; j < 2; j++) {
            int c = 32 * w + 16 * j + ln;
            float bb = b2sh[c];
#pragma unroll
            for (int r = 0; r < 4; r++) {
                int node = 16 * i + 4 * quad + r;
                if (node < nvalid)
                    Y[(size_t)(off + n0 + node) * OUT_D + c] = acc[i][j][r] + bb;
            }
        }
}

// ---------------------------------------------------------------------------
extern "C" void kernel_launch(void* const* d_in, const int* in_sizes, int n_in,
                              void* d_out, int out_size, void* d_ws, size_t ws_size,
                              hipStream_t stream)
{
    const float* X        = (const float*)d_in[0];
    const float* text_emb = (const float*)d_in[1];
    const int*   lens     = (const int*)d_in[2];
    const float* W0       = (const float*)d_in[3];
    const float* b0       = (const float*)d_in[4];
    const float* Wq       = (const float*)d_in[5];
    const float* bq       = (const float*)d_in[6];
    const float* Wk       = (const float*)d_in[7];
    // d_in[8] = bk : softmax-invariant, unused
    const float* Wv       = (const float*)d_in[9];
    const float* bv       = (const float*)d_in[10];
    const float* Wo       = (const float*)d_in[11];
    const float* bo       = (const float*)d_in[12];
    const float* W2       = (const float*)d_in[13];
    const float* b2       = (const float*)d_in[14];
    float* Y = (float*)d_out;

    char* base = (char*)d_ws;
    size_t o = 0;
    int*   offsets = (int*)(base + o);            o += 1088;
    float* qkbuf   = (float*)(base + o);          o += 262144;
    float* wvecb   = (float*)(base + o);          o += 262144;
    float* smaxb   = (float*)(base + o);          o += 1024;
    float* dinvb   = (float*)(base + o);          o += 1024;
    float* hsum    = (float*)(base + o);          o += 262144;
    float* scores  = (float*)(base + o);          o += 262144;
    unsigned short* W0sH = (unsigned short*)(base + o); o += 65536;
    unsigned short* W0sL = (unsigned short*)(base + o); o += 65536;
    unsigned short* W2sH = (unsigned short*)(base + o); o += 65536;
    unsigned short* W2sL = (unsigned short*)(base + o); o += 65536;
    unsigned short* WvsH = (unsigned short*)(base + o); o += 131072;
    unsigned short* WvsL = (unsigned short*)(base + o); o += 131072;
    unsigned short* WosH = (unsigned short*)(base + o); o += 131072;
    unsigned short* WosL = (unsigned short*)(base + o); o += 131072;

    k_prepA<<<281, 256, 0, stream>>>(text_emb, Wq, bq, Wk, W0, W2, Wv, Wo, lens,
                                     qkbuf, offsets, hsum,
                                     W0sH, W0sL, W2sH, W2sL, WvsH, WvsL, WosH, WosL);
    k_l0_mfma<<<dim3(6, B_G), 256, 0, stream>>>(X, W0sH, W0sL, b0, qkbuf, offsets, scores, hsum);
    k_mid<<<272, 256, 0, stream>>>(scores, hsum, WvsH, WvsL, WosH, WosL, bv, offsets,
                                   wvecb, smaxb, dinvb);
    k_fin_mfma<<<dim3(6, B_G), 256, 0, stream>>>(scores, wvecb, bo, W2sH, W2sL, b2, smaxb, dinvb, offsets, Y);
}